// Round 7
// baseline (623.211 us; speedup 1.0000x reference)
//
#include <hip/hip_runtime.h>
#include <cstdint>
#include <cstddef>

// ---------------------------------------------------------------------------
// GCN+LPA on MI355X.
// R7: all gather passes sit at ~2.0-2.4 TB/s of FETCH (L2-miss random-line
// ceiling). LPA steps are feature-independent -> split labels into two 32-col
// planes (3.2 MB each, fits 4 MiB per-XCD L2) and run each plane's 5-step
// chain back-to-back; edge records via nontemporal loads so the stream
// doesn't evict the plane. Logits spmm likewise plane-split (gemm64 writes
// plane buffers). xw1 spmm (25.6 MB src, can't fit) stays one pass.
// NOTE: packing assumes N < 65536 (row/col fit 16 bits). N = 50000 here.
// ---------------------------------------------------------------------------

#define WS_ALIGN(x) (((x) + 255) & ~((size_t)255))

typedef __attribute__((ext_vector_type(8))) short short8;
typedef __attribute__((ext_vector_type(4))) float floatx4;

__device__ __forceinline__ unsigned short f2bf(float f) {
    unsigned u = __float_as_uint(f);
    u += 0x7fffu + ((u >> 16) & 1u);          // round-to-nearest-even
    return (unsigned short)(u >> 16);
}
__device__ __forceinline__ float bf2f(unsigned short h) {
    return __uint_as_float(((unsigned)h) << 16);
}
__device__ __forceinline__ float sigmoidf(float x) {
    return 1.f / (1.f + __expf(-x));
}
// 8B nontemporal load of an edge record (col,w)
__device__ __forceinline__ int2 ld_nt_int2(const int2* p) {
    long long v = __builtin_nontemporal_load((const long long*)p);
    int2 r;
    r.x = (int)(unsigned)(v & 0xffffffffLL);
    r.y = (int)(v >> 32);
    return r;
}

static const int NBLK = 256;   // blocks for binning passes
#define MAXNB 256              // max coarse buckets supported (N <= 65536)

// ---------------------------------------------------------------------------
// CSR build: 2-level counting sort, LDS atomics only.
// ---------------------------------------------------------------------------
__launch_bounds__(256)
__global__ void binA_count(const int* __restrict__ row, int* __restrict__ bucket_count,
                           int* __restrict__ bases, int E, int chunk, int NB)
{
    __shared__ int hist[MAXNB];
    const int t = threadIdx.x;
    const int blk = blockIdx.x;
    if (t < NB) hist[t] = 0;
    __syncthreads();
    const int s = blk * chunk;
    const int e = min(E, s + chunk);
    for (int i = s + t; i < e; i += 256)
        atomicAdd(&hist[row[i] >> 8], 1);
    __syncthreads();
    if (t < NB)
        bases[blk * NB + t] = atomicAdd(&bucket_count[t], hist[t]);
}

__launch_bounds__(256)
__global__ void bin_scan(const int* __restrict__ bucket_count, int* __restrict__ bucket_start,
                         int NB)
{
    __shared__ int s[256];
    const int t = threadIdx.x;
    int v = (t < NB) ? bucket_count[t] : 0;
    s[t] = v;
    __syncthreads();
    for (int off = 1; off < 256; off <<= 1) {
        int u = (t >= off) ? s[t - off] : 0;
        __syncthreads();
        s[t] += u;
        __syncthreads();
    }
    int excl = s[t] - v;
    if (t <= NB) bucket_start[t] = excl;   // t==NB: total == E
}

__launch_bounds__(256)
__global__ void binA_scatter(const int* __restrict__ row, const int* __restrict__ colv,
                             const float* __restrict__ ea,
                             const int* __restrict__ bucket_start, const int* __restrict__ bases,
                             int2* __restrict__ bk, int E, int chunk, int NB)
{
    __shared__ int cur[MAXNB];
    const int t = threadIdx.x;
    const int blk = blockIdx.x;
    if (t < NB) cur[t] = bucket_start[t] + bases[blk * NB + t];
    __syncthreads();
    const int s = blk * chunk;
    const int e = min(E, s + chunk);
    for (int i = s + t; i < e; i += 256) {
        int r = row[i];
        int bin = r >> 8;
        int pos = atomicAdd(&cur[bin], 1);
        bk[pos] = make_int2(((r & 255) << 16) | colv[i], __float_as_int(ea[i]));
    }
}

__launch_bounds__(256)
__global__ void binB(const int2* __restrict__ bk, const int* __restrict__ bucket_start,
                     int* __restrict__ rowptr, int2* __restrict__ edges, int N)
{
    __shared__ int cnt[256];
    __shared__ float deg[256];
    __shared__ float inv[256];
    __shared__ int excl_s[256];
    __shared__ int cur[256];
    __shared__ int scantmp[256];
    const int b = blockIdx.x;
    const int t = threadIdx.x;
    const int s = bucket_start[b];
    const int e = bucket_start[b + 1];
    cnt[t] = 0;
    deg[t] = 0.f;
    __syncthreads();
    for (int i = s + t; i < e; i += 256) {
        int2 v = bk[i];
        int rl = ((unsigned)v.x) >> 16;
        atomicAdd(&cnt[rl], 1);
        atomicAdd(&deg[rl], __int_as_float(v.y));
    }
    __syncthreads();
    const int myc = cnt[t];
    scantmp[t] = myc;
    __syncthreads();
    for (int off = 1; off < 256; off <<= 1) {
        int u = (t >= off) ? scantmp[t - off] : 0;
        __syncthreads();
        scantmp[t] += u;
        __syncthreads();
    }
    const int excl = scantmp[t] - myc;
    excl_s[t] = excl;
    float d = deg[t];
    inv[t] = (d > 0.f) ? 1.f / d : 0.f;
    cur[t] = 0;
    const int gr = b * 256 + t;
    if (gr <= N) rowptr[gr] = s + excl;
    __syncthreads();
    for (int i = s + t; i < e; i += 256) {
        int2 v = bk[i];
        int rl = ((unsigned)v.x) >> 16;
        int c = v.x & 0xffff;
        int p = s + excl_s[rl] + atomicAdd(&cur[rl], 1);
        edges[p] = make_int2(c, __float_as_int(__int_as_float(v.y) * inv[rl]));
    }
}

// ---------------------------------------------------------------------------
// Conversions / packing
// ---------------------------------------------------------------------------
// soft f32 [N][64] -> two bf16 planes [N][32]
__global__ void split_soft_kernel(const float* __restrict__ in,
                                  unsigned short* __restrict__ p0,
                                  unsigned short* __restrict__ p1, int total)
{
    int i = blockIdx.x * 256 + threadIdx.x;
    if (i < total) {
        int r = i >> 6, f = i & 63;
        unsigned short v = f2bf(in[i]);
        if (f < 32) p0[(size_t)r * 32 + f] = v;
        else        p1[(size_t)r * 32 + f - 32] = v;
    }
}

// Pre-pack W[128,COLS] f32 -> bf16 in MFMA B-fragment order.
template<int COLS>
__global__ void pack_w_kernel(const float* __restrict__ W, unsigned short* __restrict__ Wp)
{
    const int total = (COLS / 16) * 4 * 64;
    int idx = blockIdx.x * 256 + threadIdx.x;
    if (idx >= total) return;
    const int l = idx & 63;
    const int t = (idx >> 6) & 3;
    const int ct = idx >> 8;
    const int kbase = t * 32 + (l >> 4) * 8;
    const int col = ct * 16 + (l & 15);
    unsigned short v[8];
#pragma unroll
    for (int j = 0; j < 8; ++j)
        v[j] = f2bf(W[(size_t)(kbase + j) * COLS + col]);
    uint4 o;
    o.x = (unsigned)v[0] | ((unsigned)v[1] << 16);
    o.y = (unsigned)v[2] | ((unsigned)v[3] << 16);
    o.z = (unsigned)v[4] | ((unsigned)v[5] << 16);
    o.w = (unsigned)v[6] | ((unsigned)v[7] << 16);
    *(uint4*)(Wp + (size_t)idx * 8) = o;
}

// ---------------------------------------------------------------------------
// MFMA GEMM (f32 A, fused cvt): C_bf16[M,128] = bf16(A_f32[M,128]) @ Wp.
// ---------------------------------------------------------------------------
template<int COLS>
__launch_bounds__(256)
__global__ void gemm_mfma_f32a(const float* __restrict__ A,
                               const unsigned short* __restrict__ Wp,
                               unsigned short* __restrict__ C, int M)
{
    const int wave = threadIdx.x >> 6;
    const int lane = threadIdx.x & 63;
    const int row0 = blockIdx.x * 64 + wave * 16;
    const int m = lane & 15;
    const int q = lane >> 4;

    const int arow = row0 + m;
    const bool avalid = arow < M;
    short8 a[4];
#pragma unroll
    for (int t = 0; t < 4; ++t) {
        if (avalid) {
            float4 f0 = *(const float4*)(A + (size_t)arow * 128 + t * 32 + q * 8);
            float4 f1 = *(const float4*)(A + (size_t)arow * 128 + t * 32 + q * 8 + 4);
            a[t][0] = (short)f2bf(f0.x); a[t][1] = (short)f2bf(f0.y);
            a[t][2] = (short)f2bf(f0.z); a[t][3] = (short)f2bf(f0.w);
            a[t][4] = (short)f2bf(f1.x); a[t][5] = (short)f2bf(f1.y);
            a[t][6] = (short)f2bf(f1.z); a[t][7] = (short)f2bf(f1.w);
        } else {
            a[t] = (short8)0;
        }
    }

#pragma unroll
    for (int ct = 0; ct < COLS / 16; ++ct) {
        floatx4 acc = {0.f, 0.f, 0.f, 0.f};
#pragma unroll
        for (int t = 0; t < 4; ++t) {
            short8 b = *(const short8*)(Wp + (size_t)((ct * 4 + t) * 64 + lane) * 8);
            acc = __builtin_amdgcn_mfma_f32_16x16x32_bf16(a[t], b, acc, 0, 0, 0);
        }
        const int col = ct * 16 + m;
#pragma unroll
        for (int r = 0; r < 4; ++r) {
            int orow = row0 + q * 4 + r;
            if (orow < M)
                C[(size_t)orow * COLS + col] = f2bf(acc[r]);
        }
    }
}

// MFMA GEMM (bf16 A, COLS=64) writing two 32-col plane buffers.
__launch_bounds__(256)
__global__ void gemm_mfma64_planes(const unsigned short* __restrict__ A,
                                   const unsigned short* __restrict__ Wp,
                                   unsigned short* __restrict__ C0,
                                   unsigned short* __restrict__ C1, int M)
{
    const int wave = threadIdx.x >> 6;
    const int lane = threadIdx.x & 63;
    const int row0 = blockIdx.x * 64 + wave * 16;
    const int m = lane & 15;
    const int q = lane >> 4;

    const int arow = row0 + m;
    const bool avalid = arow < M;
    short8 a[4];
#pragma unroll
    for (int t = 0; t < 4; ++t) {
        if (avalid)
            a[t] = *(const short8*)(A + (size_t)arow * 128 + t * 32 + q * 8);
        else
            a[t] = (short8)0;
    }

#pragma unroll
    for (int ct = 0; ct < 4; ++ct) {
        floatx4 acc = {0.f, 0.f, 0.f, 0.f};
#pragma unroll
        for (int t = 0; t < 4; ++t) {
            short8 b = *(const short8*)(Wp + (size_t)((ct * 4 + t) * 64 + lane) * 8);
            acc = __builtin_amdgcn_mfma_f32_16x16x32_bf16(a[t], b, acc, 0, 0, 0);
        }
        unsigned short* C = (ct < 2) ? C0 : C1;
        const int ccol = (ct < 2) ? (ct * 16 + m) : (ct * 16 + m - 32);
#pragma unroll
        for (int r = 0; r < 4; ++r) {
            int orow = row0 + q * 4 + r;
            if (orow < M)
                C[(size_t)orow * 32 + ccol] = f2bf(acc[r]);
        }
    }
}

// ---------------------------------------------------------------------------
// SpMM F=128, bf16 packed src, bias+relu, bf16 packed output. One wave/row,
// 8-deep bursts, nontemporal edge loads.
// ---------------------------------------------------------------------------
__launch_bounds__(256)
__global__ void spmm128_relu(const int* __restrict__ rowptr, const int2* __restrict__ edges,
                             const unsigned* __restrict__ srcA,
                             const float* __restrict__ bias, unsigned* __restrict__ out, int n)
{
    const int row = blockIdx.x * 4 + (threadIdx.x >> 6);
    const int lane = threadIdx.x & 63;
    if (row >= n) return;
    const int s = rowptr[row];
    const int e = rowptr[row + 1];

    float ax[8], ay[8];
#pragma unroll
    for (int j = 0; j < 8; ++j) { ax[j] = 0.f; ay[j] = 0.f; }
    int i = s;
    for (; i + 8 <= e; i += 8) {
        int2 ed[8];
        unsigned u[8];
#pragma unroll
        for (int j = 0; j < 8; ++j) ed[j] = ld_nt_int2(&edges[i + j]);
#pragma unroll
        for (int j = 0; j < 8; ++j) u[j] = srcA[(size_t)ed[j].x * 64 + lane];
#pragma unroll
        for (int j = 0; j < 8; ++j) {
            float w = __int_as_float(ed[j].y);
            ax[j] = fmaf(w, __uint_as_float(u[j] << 16), ax[j]);
            ay[j] = fmaf(w, __uint_as_float(u[j] & 0xffff0000u), ay[j]);
        }
    }
    for (; i < e; ++i) {
        int2 e0 = ld_nt_int2(&edges[i]);
        unsigned u0 = srcA[(size_t)e0.x * 64 + lane];
        float w0 = __int_as_float(e0.y);
        ax[0] = fmaf(w0, __uint_as_float(u0 << 16), ax[0]);
        ay[0] = fmaf(w0, __uint_as_float(u0 & 0xffff0000u), ay[0]);
    }
    float vx = ((ax[0] + ax[1]) + (ax[2] + ax[3])) + ((ax[4] + ax[5]) + (ax[6] + ax[7]));
    float vy = ((ay[0] + ay[1]) + (ay[2] + ay[3])) + ((ay[4] + ay[5]) + (ay[6] + ay[7]));
    float2 b = *(const float2*)(bias + lane * 2);
    vx = fmaxf(vx + b.x, 0.f);
    vy = fmaxf(vy + b.y, 0.f);
    out[(size_t)row * 64 + lane] = (unsigned)f2bf(vx) | ((unsigned)f2bf(vy) << 16);
}

// ---------------------------------------------------------------------------
// Plane SpMM F=32: src plane [N][32] bf16 (3.2 MB, fits per-XCD L2).
// Wave = 1 row; lanes 0-31 = features of even edge, lanes 32-63 = odd edge;
// fold with one shfl. ACT: 0 -> bf16 plane out; 2 -> bias+sigmoid f32 out
// (strided [N][64] at plane_off); 3 -> sigmoid f32 out.
// ---------------------------------------------------------------------------
template<int ACT>
__launch_bounds__(256)
__global__ void spmm32_plane(const int* __restrict__ rowptr, const int2* __restrict__ edges,
                             const unsigned short* __restrict__ src,
                             const float* __restrict__ bias,
                             void* __restrict__ out, int plane_off, int n)
{
    const int row = blockIdx.x * 4 + (threadIdx.x >> 6);
    const int lane = threadIdx.x & 63;
    const int f = lane & 31;
    const int half = lane >> 5;
    if (row >= n) return;
    const int s = rowptr[row];
    const int e = rowptr[row + 1];

    float a[4] = {0.f, 0.f, 0.f, 0.f};
    int i = s;
    while (i + 16 <= e) {                       // 8 paired loads = 16 edges
        int2 ed[8];
        float sv[8];
#pragma unroll
        for (int j = 0; j < 8; ++j) ed[j] = ld_nt_int2(&edges[i + 2 * j + half]);
#pragma unroll
        for (int j = 0; j < 8; ++j) sv[j] = bf2f(src[(size_t)ed[j].x * 32 + f]);
#pragma unroll
        for (int j = 0; j < 8; ++j) a[j & 3] = fmaf(__int_as_float(ed[j].y), sv[j], a[j & 3]);
        i += 16;
    }
    while (i + 2 <= e) {
        int2 ed = ld_nt_int2(&edges[i + half]);
        a[0] = fmaf(__int_as_float(ed.y), bf2f(src[(size_t)ed.x * 32 + f]), a[0]);
        i += 2;
    }
    if (i < e) {                                // odd leftover: half 0 only
        int2 ed = ld_nt_int2(&edges[i]);
        if (half == 0)
            a[1] = fmaf(__int_as_float(ed.y), bf2f(src[(size_t)ed.x * 32 + f]), a[1]);
    }
    float v = (a[0] + a[1]) + (a[2] + a[3]);
    v += __shfl_down(v, 32);
    if (half == 0) {
        if (ACT == 0) {
            ((unsigned short*)out)[(size_t)row * 32 + f] = f2bf(v);
        } else {
            float x = v;
            if (ACT == 2) x += bias[plane_off + f];
            x = sigmoidf(x);
            ((float*)out)[(size_t)row * 64 + plane_off + f] = x;
        }
    }
}

// ---------------------------------------------------------------------------
extern "C" void kernel_launch(void* const* d_in, const int* in_sizes, int n_in,
                              void* d_out, int out_size, void* d_ws, size_t ws_size,
                              hipStream_t stream)
{
    const float* x    = (const float*)d_in[0];
    const float* soft = (const float*)d_in[1];
    const float* ea   = (const float*)d_in[2];
    const float* w1   = (const float*)d_in[3];
    const float* b1   = (const float*)d_in[4];
    const float* w2   = (const float*)d_in[5];
    const float* b2   = (const float*)d_in[6];
    const int*   eidx = (const int*)d_in[7];

    const int N = in_sizes[0] / 128;
    const int E = in_sizes[2];
    const int* row  = eidx;
    const int* colv = eidx + E;
    const int NB = (N + 255) / 256;            // coarse buckets (<= 256)
    const int chunk = (E + NBLK - 1) / NBLK;

    uint8_t* ws = (uint8_t*)d_ws;
    size_t off = 0;
    auto alloc = [&](size_t bytes) -> void* {
        void* p = ws + off;
        off += WS_ALIGN(bytes);
        return p;
    };
    int*  bucket_count = (int*) alloc((size_t)NB * 4);
    int*  bucket_start = (int*) alloc(((size_t)NB + 1) * 4);
    int*  bases        = (int*) alloc((size_t)NBLK * NB * 4);
    int*  rowptr       = (int*) alloc(((size_t)N + 1) * 4);
    int2* bk           = (int2*)alloc((size_t)E * 8);
    int2* edges        = (int2*)alloc((size_t)E * 8);
    unsigned short* w1p   = (unsigned short*)alloc((size_t)128 * 128 * 2);
    unsigned short* w2p   = (unsigned short*)alloc((size_t)128 * 64 * 2);
    unsigned short* xw1b  = (unsigned short*)alloc((size_t)N * 128 * 2);
    unsigned short* hb    = (unsigned short*)alloc((size_t)N * 128 * 2);
    unsigned short* logp0 = (unsigned short*)alloc((size_t)N * 32 * 2);
    unsigned short* logp1 = (unsigned short*)alloc((size_t)N * 32 * 2);
    unsigned short* softp0= (unsigned short*)alloc((size_t)N * 32 * 2);
    unsigned short* softp1= (unsigned short*)alloc((size_t)N * 32 * 2);
    unsigned short* labP  = (unsigned short*)alloc((size_t)N * 32 * 2);
    unsigned short* labQ  = (unsigned short*)alloc((size_t)N * 32 * 2);

    float* out0 = (float*)d_out;             // x_out [N,64]
    float* out1 = out0 + (size_t)N * 64;     // labels [N,64]

    hipMemsetAsync(bucket_count, 0, (size_t)NB * 4, stream);

    // CSR build: counting sort, LDS atomics only (+50k block-level globals)
    binA_count<<<NBLK, 256, 0, stream>>>(row, bucket_count, bases, E, chunk, NB);
    bin_scan<<<1, 256, 0, stream>>>(bucket_count, bucket_start, NB);
    binA_scatter<<<NBLK, 256, 0, stream>>>(row, colv, ea, bucket_start, bases, bk, E, chunk, NB);
    binB<<<NB, 256, 0, stream>>>(bk, bucket_start, rowptr, edges, N);

    // soft -> 2 bf16 planes; w1, w2 -> packed bf16 fragments
    const int tot = N * 64;
    split_soft_kernel<<<(tot + 255) / 256, 256, 0, stream>>>(soft, softp0, softp1, tot);
    pack_w_kernel<128><<<8, 256, 0, stream>>>(w1, w1p);
    pack_w_kernel<64><<<4, 256, 0, stream>>>(w2, w2p);

    const int gGemm = (N + 63) / 64;
    const int gSp   = (N + 3) / 4;

    // ---- GCN chain ----
    gemm_mfma_f32a<128><<<gGemm, 256, 0, stream>>>(x, w1p, xw1b, N);                  // xw1
    spmm128_relu<<<gSp, 256, 0, stream>>>(rowptr, edges, (const unsigned*)xw1b,
                                          b1, (unsigned*)hb, N);                      // h
    gemm_mfma64_planes<<<gGemm, 256, 0, stream>>>(hb, w2p, logp0, logp1, N);          // logits
    spmm32_plane<2><<<gSp, 256, 0, stream>>>(rowptr, edges, logp0, b2, out0, 0, N);   // out0 lo
    spmm32_plane<2><<<gSp, 256, 0, stream>>>(rowptr, edges, logp1, b2, out0, 32, N);  // out0 hi

    // ---- LPA plane 0 chain (5 steps, 3.2 MB L2-resident plane) ----
    spmm32_plane<0><<<gSp, 256, 0, stream>>>(rowptr, edges, softp0, nullptr, labP, 0, N);
    spmm32_plane<0><<<gSp, 256, 0, stream>>>(rowptr, edges, labP, nullptr, labQ, 0, N);
    spmm32_plane<0><<<gSp, 256, 0, stream>>>(rowptr, edges, labQ, nullptr, labP, 0, N);
    spmm32_plane<0><<<gSp, 256, 0, stream>>>(rowptr, edges, labP, nullptr, labQ, 0, N);
    spmm32_plane<3><<<gSp, 256, 0, stream>>>(rowptr, edges, labQ, nullptr, out1, 0, N);

    // ---- LPA plane 1 chain ----
    spmm32_plane<0><<<gSp, 256, 0, stream>>>(rowptr, edges, softp1, nullptr, labP, 0, N);
    spmm32_plane<0><<<gSp, 256, 0, stream>>>(rowptr, edges, labP, nullptr, labQ, 0, N);
    spmm32_plane<0><<<gSp, 256, 0, stream>>>(rowptr, edges, labQ, nullptr, labP, 0, N);
    spmm32_plane<0><<<gSp, 256, 0, stream>>>(rowptr, edges, labP, nullptr, labQ, 0, N);
    spmm32_plane<3><<<gSp, 256, 0, stream>>>(rowptr, edges, labQ, nullptr, out1, 32, N);
}

// Round 8
// 317.800 us; speedup vs baseline: 1.9610x; 1.9610x over previous
//
#include <hip/hip_runtime.h>
#include <cstdint>
#include <cstddef>

// ---------------------------------------------------------------------------
// GCN+LPA on MI355X.
// R8: R7 falsified the fetch-bound theory (plane FETCH dropped to compulsory
// 3.2MBx8 but time regressed): gather passes are ADDRESS/transaction bound
// (~64 lane-addresses per edge through the TA at ~21G/s). Keep R6's minimal
// 5-pass structure; halve addresses per edge: each lane loads 4-8B, 32 lanes
// cover a row, one wave-gather serves 2 edges (half-wave per edge, folded by
// one shfl_down(32) - mechanism correctness-proven in R7's plane kernels).
// NOTE: packing assumes N < 65536 (row/col fit 16 bits). N = 50000 here.
// ---------------------------------------------------------------------------

#define WS_ALIGN(x) (((x) + 255) & ~((size_t)255))

typedef __attribute__((ext_vector_type(8))) short short8;
typedef __attribute__((ext_vector_type(4))) float floatx4;

__device__ __forceinline__ unsigned short f2bf(float f) {
    unsigned u = __float_as_uint(f);
    u += 0x7fffu + ((u >> 16) & 1u);          // round-to-nearest-even
    return (unsigned short)(u >> 16);
}
__device__ __forceinline__ float bf_lo(unsigned u) { return __uint_as_float(u << 16); }
__device__ __forceinline__ float bf_hi(unsigned u) { return __uint_as_float(u & 0xffff0000u); }
__device__ __forceinline__ float bf2f(unsigned short h) {
    return __uint_as_float(((unsigned)h) << 16);
}
__device__ __forceinline__ unsigned pack_bf2(float a, float b) {
    return (unsigned)f2bf(a) | ((unsigned)f2bf(b) << 16);
}
__device__ __forceinline__ float sigmoidf(float x) {
    return 1.f / (1.f + __expf(-x));
}
__device__ __forceinline__ int2 ld_nt_int2(const int2* p) {
    long long v = __builtin_nontemporal_load((const long long*)p);
    int2 r;
    r.x = (int)(unsigned)(v & 0xffffffffLL);
    r.y = (int)(v >> 32);
    return r;
}

static const int NBLK = 256;   // blocks for binning passes
#define MAXNB 256              // max coarse buckets supported (N <= 65536)

// ---------------------------------------------------------------------------
// CSR build: 2-level counting sort, LDS atomics only.
// ---------------------------------------------------------------------------
__launch_bounds__(256)
__global__ void binA_count(const int* __restrict__ row, int* __restrict__ bucket_count,
                           int* __restrict__ bases, int E, int chunk, int NB)
{
    __shared__ int hist[MAXNB];
    const int t = threadIdx.x;
    const int blk = blockIdx.x;
    if (t < NB) hist[t] = 0;
    __syncthreads();
    const int s = blk * chunk;
    const int e = min(E, s + chunk);
    for (int i = s + t; i < e; i += 256)
        atomicAdd(&hist[row[i] >> 8], 1);
    __syncthreads();
    if (t < NB)
        bases[blk * NB + t] = atomicAdd(&bucket_count[t], hist[t]);
}

__launch_bounds__(256)
__global__ void bin_scan(const int* __restrict__ bucket_count, int* __restrict__ bucket_start,
                         int NB)
{
    __shared__ int s[256];
    const int t = threadIdx.x;
    int v = (t < NB) ? bucket_count[t] : 0;
    s[t] = v;
    __syncthreads();
    for (int off = 1; off < 256; off <<= 1) {
        int u = (t >= off) ? s[t - off] : 0;
        __syncthreads();
        s[t] += u;
        __syncthreads();
    }
    int excl = s[t] - v;
    if (t <= NB) bucket_start[t] = excl;   // t==NB: total == E
}

__launch_bounds__(256)
__global__ void binA_scatter(const int* __restrict__ row, const int* __restrict__ colv,
                             const float* __restrict__ ea,
                             const int* __restrict__ bucket_start, const int* __restrict__ bases,
                             int2* __restrict__ bk, int E, int chunk, int NB)
{
    __shared__ int cur[MAXNB];
    const int t = threadIdx.x;
    const int blk = blockIdx.x;
    if (t < NB) cur[t] = bucket_start[t] + bases[blk * NB + t];
    __syncthreads();
    const int s = blk * chunk;
    const int e = min(E, s + chunk);
    for (int i = s + t; i < e; i += 256) {
        int r = row[i];
        int bin = r >> 8;
        int pos = atomicAdd(&cur[bin], 1);
        bk[pos] = make_int2(((r & 255) << 16) | colv[i], __float_as_int(ea[i]));
    }
}

__launch_bounds__(256)
__global__ void binB(const int2* __restrict__ bk, const int* __restrict__ bucket_start,
                     int* __restrict__ rowptr, int2* __restrict__ edges, int N)
{
    __shared__ int cnt[256];
    __shared__ float deg[256];
    __shared__ float inv[256];
    __shared__ int excl_s[256];
    __shared__ int cur[256];
    __shared__ int scantmp[256];
    const int b = blockIdx.x;
    const int t = threadIdx.x;
    const int s = bucket_start[b];
    const int e = bucket_start[b + 1];
    cnt[t] = 0;
    deg[t] = 0.f;
    __syncthreads();
    for (int i = s + t; i < e; i += 256) {
        int2 v = bk[i];
        int rl = ((unsigned)v.x) >> 16;
        atomicAdd(&cnt[rl], 1);
        atomicAdd(&deg[rl], __int_as_float(v.y));
    }
    __syncthreads();
    const int myc = cnt[t];
    scantmp[t] = myc;
    __syncthreads();
    for (int off = 1; off < 256; off <<= 1) {
        int u = (t >= off) ? scantmp[t - off] : 0;
        __syncthreads();
        scantmp[t] += u;
        __syncthreads();
    }
    const int excl = scantmp[t] - myc;
    excl_s[t] = excl;
    float d = deg[t];
    inv[t] = (d > 0.f) ? 1.f / d : 0.f;
    cur[t] = 0;
    const int gr = b * 256 + t;
    if (gr <= N) rowptr[gr] = s + excl;
    __syncthreads();
    for (int i = s + t; i < e; i += 256) {
        int2 v = bk[i];
        int rl = ((unsigned)v.x) >> 16;
        int c = v.x & 0xffff;
        int p = s + excl_s[rl] + atomicAdd(&cur[rl], 1);
        edges[p] = make_int2(c, __float_as_int(__int_as_float(v.y) * inv[rl]));
    }
}

// ---------------------------------------------------------------------------
// Conversions / packing
// ---------------------------------------------------------------------------
__global__ void f32_to_bf16_kernel(const float* __restrict__ in, unsigned short* __restrict__ out,
                                   int n2)  // n2 = n/2 pairs
{
    int i = blockIdx.x * 256 + threadIdx.x;
    if (i < n2) {
        float2 v = ((const float2*)in)[i];
        ((unsigned*)out)[i] = pack_bf2(v.x, v.y);
    }
}

// Pre-pack W[128,COLS] f32 -> bf16 in MFMA B-fragment order.
template<int COLS>
__global__ void pack_w_kernel(const float* __restrict__ W, unsigned short* __restrict__ Wp)
{
    const int total = (COLS / 16) * 4 * 64;
    int idx = blockIdx.x * 256 + threadIdx.x;
    if (idx >= total) return;
    const int l = idx & 63;
    const int t = (idx >> 6) & 3;
    const int ct = idx >> 8;
    const int kbase = t * 32 + (l >> 4) * 8;
    const int col = ct * 16 + (l & 15);
    unsigned short v[8];
#pragma unroll
    for (int j = 0; j < 8; ++j)
        v[j] = f2bf(W[(size_t)(kbase + j) * COLS + col]);
    uint4 o;
    o.x = (unsigned)v[0] | ((unsigned)v[1] << 16);
    o.y = (unsigned)v[2] | ((unsigned)v[3] << 16);
    o.z = (unsigned)v[4] | ((unsigned)v[5] << 16);
    o.w = (unsigned)v[6] | ((unsigned)v[7] << 16);
    *(uint4*)(Wp + (size_t)idx * 8) = o;
}

// ---------------------------------------------------------------------------
// MFMA GEMM (f32 A, fused cvt): C_bf16[M,128] = bf16(A_f32[M,128]) @ Wp.
// ---------------------------------------------------------------------------
template<int COLS>
__launch_bounds__(256)
__global__ void gemm_mfma_f32a(const float* __restrict__ A,
                               const unsigned short* __restrict__ Wp,
                               unsigned short* __restrict__ C, int M)
{
    const int wave = threadIdx.x >> 6;
    const int lane = threadIdx.x & 63;
    const int row0 = blockIdx.x * 64 + wave * 16;
    const int m = lane & 15;
    const int q = lane >> 4;

    const int arow = row0 + m;
    const bool avalid = arow < M;
    short8 a[4];
#pragma unroll
    for (int t = 0; t < 4; ++t) {
        if (avalid) {
            float4 f0 = *(const float4*)(A + (size_t)arow * 128 + t * 32 + q * 8);
            float4 f1 = *(const float4*)(A + (size_t)arow * 128 + t * 32 + q * 8 + 4);
            a[t][0] = (short)f2bf(f0.x); a[t][1] = (short)f2bf(f0.y);
            a[t][2] = (short)f2bf(f0.z); a[t][3] = (short)f2bf(f0.w);
            a[t][4] = (short)f2bf(f1.x); a[t][5] = (short)f2bf(f1.y);
            a[t][6] = (short)f2bf(f1.z); a[t][7] = (short)f2bf(f1.w);
        } else {
            a[t] = (short8)0;
        }
    }

#pragma unroll
    for (int ct = 0; ct < COLS / 16; ++ct) {
        floatx4 acc = {0.f, 0.f, 0.f, 0.f};
#pragma unroll
        for (int t = 0; t < 4; ++t) {
            short8 b = *(const short8*)(Wp + (size_t)((ct * 4 + t) * 64 + lane) * 8);
            acc = __builtin_amdgcn_mfma_f32_16x16x32_bf16(a[t], b, acc, 0, 0, 0);
        }
        const int col = ct * 16 + m;
#pragma unroll
        for (int r = 0; r < 4; ++r) {
            int orow = row0 + q * 4 + r;
            if (orow < M)
                C[(size_t)orow * COLS + col] = f2bf(acc[r]);
        }
    }
}

// MFMA GEMM (bf16 A): same structure, A already bf16.
template<int COLS>
__launch_bounds__(256)
__global__ void gemm_mfma(const unsigned short* __restrict__ A,
                          const unsigned short* __restrict__ Wp,
                          unsigned short* __restrict__ C, int M)
{
    const int wave = threadIdx.x >> 6;
    const int lane = threadIdx.x & 63;
    const int row0 = blockIdx.x * 64 + wave * 16;
    const int m = lane & 15;
    const int q = lane >> 4;

    const int arow = row0 + m;
    const bool avalid = arow < M;
    short8 a[4];
#pragma unroll
    for (int t = 0; t < 4; ++t) {
        if (avalid)
            a[t] = *(const short8*)(A + (size_t)arow * 128 + t * 32 + q * 8);
        else
            a[t] = (short8)0;
    }

#pragma unroll
    for (int ct = 0; ct < COLS / 16; ++ct) {
        floatx4 acc = {0.f, 0.f, 0.f, 0.f};
#pragma unroll
        for (int t = 0; t < 4; ++t) {
            short8 b = *(const short8*)(Wp + (size_t)((ct * 4 + t) * 64 + lane) * 8);
            acc = __builtin_amdgcn_mfma_f32_16x16x32_bf16(a[t], b, acc, 0, 0, 0);
        }
        const int col = ct * 16 + m;
#pragma unroll
        for (int r = 0; r < 4; ++r) {
            int orow = row0 + q * 4 + r;
            if (orow < M)
                C[(size_t)orow * COLS + col] = f2bf(acc[r]);
        }
    }
}

// ---------------------------------------------------------------------------
// FUSED 1 (paired-edge): F=128 stream (xw1 -> h, bias+relu)
//                      + F=64 stream (soft -> lab1).
// Wave = 1 row; lanes 0-31 handle even edge, 32-63 odd edge; lane covers
// 4 feats (uint2) of xw1 and 2 feats (uint) of soft. Fold via shfl_down(32).
// ---------------------------------------------------------------------------
__launch_bounds__(256)
__global__ void fused1_pair(const int* __restrict__ rowptr, const int2* __restrict__ edges,
                            const uint2* __restrict__ srcA,      // xw1 [N][32] uint2
                            const unsigned* __restrict__ srcB,   // soft [N][32] uint
                            const float* __restrict__ bias,
                            uint2* __restrict__ outA,            // h [N][32] uint2
                            unsigned* __restrict__ outB,         // lab1 [N][32] uint
                            int n)
{
    const int row = blockIdx.x * 4 + (threadIdx.x >> 6);
    const int lane = threadIdx.x & 63;
    const int f = lane & 31;
    const int half = lane >> 5;
    if (row >= n) return;
    const int s = rowptr[row];
    const int e = rowptr[row + 1];

    float a0[4], a1[4], b0[2], b1[2];
#pragma unroll
    for (int j = 0; j < 4; ++j) { a0[j] = 0.f; a1[j] = 0.f; }
    b0[0] = b0[1] = b1[0] = b1[1] = 0.f;

    int i = s;
    for (; i + 8 <= e; i += 8) {                 // 4 paired instrs = 8 edges
        int2 ed[4]; uint2 ua[4]; unsigned ub[4];
#pragma unroll
        for (int j = 0; j < 4; ++j) ed[j] = ld_nt_int2(&edges[i + 2 * j + half]);
#pragma unroll
        for (int j = 0; j < 4; ++j) ua[j] = srcA[(size_t)ed[j].x * 32 + f];
#pragma unroll
        for (int j = 0; j < 4; ++j) ub[j] = srcB[(size_t)ed[j].x * 32 + f];
#pragma unroll
        for (int j = 0; j < 4; ++j) {
            float w = __int_as_float(ed[j].y);
            float* A = (j & 1) ? a1 : a0;
            float* B = (j & 1) ? b1 : b0;
            A[0] = fmaf(w, bf_lo(ua[j].x), A[0]);
            A[1] = fmaf(w, bf_hi(ua[j].x), A[1]);
            A[2] = fmaf(w, bf_lo(ua[j].y), A[2]);
            A[3] = fmaf(w, bf_hi(ua[j].y), A[3]);
            B[0] = fmaf(w, bf_lo(ub[j]), B[0]);
            B[1] = fmaf(w, bf_hi(ub[j]), B[1]);
        }
    }
    for (; i + 2 <= e; i += 2) {                 // paired tail
        int2 ed = ld_nt_int2(&edges[i + half]);
        float w = __int_as_float(ed.y);
        uint2 ua = srcA[(size_t)ed.x * 32 + f];
        unsigned ub = srcB[(size_t)ed.x * 32 + f];
        a0[0] = fmaf(w, bf_lo(ua.x), a0[0]);
        a0[1] = fmaf(w, bf_hi(ua.x), a0[1]);
        a0[2] = fmaf(w, bf_lo(ua.y), a0[2]);
        a0[3] = fmaf(w, bf_hi(ua.y), a0[3]);
        b0[0] = fmaf(w, bf_lo(ub), b0[0]);
        b0[1] = fmaf(w, bf_hi(ub), b0[1]);
    }
    if (i < e && half == 0) {                    // odd leftover: half 0 only
        int2 ed = ld_nt_int2(&edges[i]);
        float w = __int_as_float(ed.y);
        uint2 ua = srcA[(size_t)ed.x * 32 + f];
        unsigned ub = srcB[(size_t)ed.x * 32 + f];
        a1[0] = fmaf(w, bf_lo(ua.x), a1[0]);
        a1[1] = fmaf(w, bf_hi(ua.x), a1[1]);
        a1[2] = fmaf(w, bf_lo(ua.y), a1[2]);
        a1[3] = fmaf(w, bf_hi(ua.y), a1[3]);
        b1[0] = fmaf(w, bf_lo(ub), b1[0]);
        b1[1] = fmaf(w, bf_hi(ub), b1[1]);
    }
    float A0 = a0[0] + a1[0], A1 = a0[1] + a1[1];
    float A2 = a0[2] + a1[2], A3 = a0[3] + a1[3];
    float B0 = b0[0] + b1[0], B1 = b0[1] + b1[1];
    A0 += __shfl_down(A0, 32); A1 += __shfl_down(A1, 32);
    A2 += __shfl_down(A2, 32); A3 += __shfl_down(A3, 32);
    B0 += __shfl_down(B0, 32); B1 += __shfl_down(B1, 32);
    if (half == 0) {
        float4 bb = *(const float4*)(bias + 4 * f);
        A0 = fmaxf(A0 + bb.x, 0.f);
        A1 = fmaxf(A1 + bb.y, 0.f);
        A2 = fmaxf(A2 + bb.z, 0.f);
        A3 = fmaxf(A3 + bb.w, 0.f);
        uint2 o;
        o.x = pack_bf2(A0, A1);
        o.y = pack_bf2(A2, A3);
        outA[(size_t)row * 32 + f] = o;
        outB[(size_t)row * 32 + f] = pack_bf2(B0, B1);
    }
}

// ---------------------------------------------------------------------------
// FUSED 2 (paired-edge): A: logits -> out0 (bias+sigmoid, f32).
//                        B: lab1 -> lab2 (bf16 packed).
// ---------------------------------------------------------------------------
__launch_bounds__(256)
__global__ void fused2_pair(const int* __restrict__ rowptr, const int2* __restrict__ edges,
                            const unsigned* __restrict__ srcA,   // logits [N][32] uint
                            const unsigned* __restrict__ srcB,   // lab1 [N][32] uint
                            const float* __restrict__ bias,
                            float* __restrict__ outA,            // out0 f32 [N][64]
                            unsigned* __restrict__ outB,         // lab2 [N][32] uint
                            int n)
{
    const int row = blockIdx.x * 4 + (threadIdx.x >> 6);
    const int lane = threadIdx.x & 63;
    const int f = lane & 31;
    const int half = lane >> 5;
    if (row >= n) return;
    const int s = rowptr[row];
    const int e = rowptr[row + 1];

    float a0[2], a1[2], b0[2], b1[2];
    a0[0] = a0[1] = a1[0] = a1[1] = 0.f;
    b0[0] = b0[1] = b1[0] = b1[1] = 0.f;

    int i = s;
    for (; i + 8 <= e; i += 8) {
        int2 ed[4]; unsigned ua[4], ub[4];
#pragma unroll
        for (int j = 0; j < 4; ++j) ed[j] = ld_nt_int2(&edges[i + 2 * j + half]);
#pragma unroll
        for (int j = 0; j < 4; ++j) ua[j] = srcA[(size_t)ed[j].x * 32 + f];
#pragma unroll
        for (int j = 0; j < 4; ++j) ub[j] = srcB[(size_t)ed[j].x * 32 + f];
#pragma unroll
        for (int j = 0; j < 4; ++j) {
            float w = __int_as_float(ed[j].y);
            float* A = (j & 1) ? a1 : a0;
            float* B = (j & 1) ? b1 : b0;
            A[0] = fmaf(w, bf_lo(ua[j]), A[0]);
            A[1] = fmaf(w, bf_hi(ua[j]), A[1]);
            B[0] = fmaf(w, bf_lo(ub[j]), B[0]);
            B[1] = fmaf(w, bf_hi(ub[j]), B[1]);
        }
    }
    for (; i + 2 <= e; i += 2) {
        int2 ed = ld_nt_int2(&edges[i + half]);
        float w = __int_as_float(ed.y);
        unsigned ua = srcA[(size_t)ed.x * 32 + f];
        unsigned ub = srcB[(size_t)ed.x * 32 + f];
        a0[0] = fmaf(w, bf_lo(ua), a0[0]);
        a0[1] = fmaf(w, bf_hi(ua), a0[1]);
        b0[0] = fmaf(w, bf_lo(ub), b0[0]);
        b0[1] = fmaf(w, bf_hi(ub), b0[1]);
    }
    if (i < e && half == 0) {
        int2 ed = ld_nt_int2(&edges[i]);
        float w = __int_as_float(ed.y);
        unsigned ua = srcA[(size_t)ed.x * 32 + f];
        unsigned ub = srcB[(size_t)ed.x * 32 + f];
        a1[0] = fmaf(w, bf_lo(ua), a1[0]);
        a1[1] = fmaf(w, bf_hi(ua), a1[1]);
        b1[0] = fmaf(w, bf_lo(ub), b1[0]);
        b1[1] = fmaf(w, bf_hi(ub), b1[1]);
    }
    float A0 = a0[0] + a1[0], A1 = a0[1] + a1[1];
    float B0 = b0[0] + b1[0], B1 = b0[1] + b1[1];
    A0 += __shfl_down(A0, 32); A1 += __shfl_down(A1, 32);
    B0 += __shfl_down(B0, 32); B1 += __shfl_down(B1, 32);
    if (half == 0) {
        float2 bb = *(const float2*)(bias + 2 * f);
        float2 o;
        o.x = sigmoidf(A0 + bb.x);
        o.y = sigmoidf(A1 + bb.y);
        *(float2*)(outA + (size_t)row * 64 + 2 * f) = o;
        outB[(size_t)row * 32 + f] = pack_bf2(B0, B1);
    }
}

// ---------------------------------------------------------------------------
// Solo SpMM F=64 (paired-edge). ACT: 0 none (bf16 out), 3 sigmoid (f32 out).
// ---------------------------------------------------------------------------
template<int ACT>
__launch_bounds__(256)
__global__ void spmm64_pair(const int* __restrict__ rowptr, const int2* __restrict__ edges,
                            const unsigned* __restrict__ src,    // [N][32] uint
                            void* __restrict__ out, int n)
{
    const int row = blockIdx.x * 4 + (threadIdx.x >> 6);
    const int lane = threadIdx.x & 63;
    const int f = lane & 31;
    const int half = lane >> 5;
    if (row >= n) return;
    const int s = rowptr[row];
    const int e = rowptr[row + 1];

    float a[4][2];
#pragma unroll
    for (int j = 0; j < 4; ++j) { a[j][0] = 0.f; a[j][1] = 0.f; }

    int i = s;
    for (; i + 8 <= e; i += 8) {
        int2 ed[4]; unsigned u[4];
#pragma unroll
        for (int j = 0; j < 4; ++j) ed[j] = ld_nt_int2(&edges[i + 2 * j + half]);
#pragma unroll
        for (int j = 0; j < 4; ++j) u[j] = src[(size_t)ed[j].x * 32 + f];
#pragma unroll
        for (int j = 0; j < 4; ++j) {
            float w = __int_as_float(ed[j].y);
            a[j][0] = fmaf(w, bf_lo(u[j]), a[j][0]);
            a[j][1] = fmaf(w, bf_hi(u[j]), a[j][1]);
        }
    }
    for (; i + 2 <= e; i += 2) {
        int2 ed = ld_nt_int2(&edges[i + half]);
        float w = __int_as_float(ed.y);
        unsigned u = src[(size_t)ed.x * 32 + f];
        a[0][0] = fmaf(w, bf_lo(u), a[0][0]);
        a[0][1] = fmaf(w, bf_hi(u), a[0][1]);
    }
    if (i < e && half == 0) {
        int2 ed = ld_nt_int2(&edges[i]);
        float w = __int_as_float(ed.y);
        unsigned u = src[(size_t)ed.x * 32 + f];
        a[1][0] = fmaf(w, bf_lo(u), a[1][0]);
        a[1][1] = fmaf(w, bf_hi(u), a[1][1]);
    }
    float v0 = (a[0][0] + a[1][0]) + (a[2][0] + a[3][0]);
    float v1 = (a[0][1] + a[1][1]) + (a[2][1] + a[3][1]);
    v0 += __shfl_down(v0, 32);
    v1 += __shfl_down(v1, 32);
    if (half == 0) {
        if (ACT == 0) {
            ((unsigned*)out)[(size_t)row * 32 + f] = pack_bf2(v0, v1);
        } else {
            float2 o;
            o.x = sigmoidf(v0);
            o.y = sigmoidf(v1);
            *(float2*)((float*)out + (size_t)row * 64 + 2 * f) = o;
        }
    }
}

// ---------------------------------------------------------------------------
extern "C" void kernel_launch(void* const* d_in, const int* in_sizes, int n_in,
                              void* d_out, int out_size, void* d_ws, size_t ws_size,
                              hipStream_t stream)
{
    const float* x    = (const float*)d_in[0];
    const float* soft = (const float*)d_in[1];
    const float* ea   = (const float*)d_in[2];
    const float* w1   = (const float*)d_in[3];
    const float* b1   = (const float*)d_in[4];
    const float* w2   = (const float*)d_in[5];
    const float* b2   = (const float*)d_in[6];
    const int*   eidx = (const int*)d_in[7];

    const int N = in_sizes[0] / 128;
    const int E = in_sizes[2];
    const int* row  = eidx;
    const int* colv = eidx + E;
    const int NB = (N + 255) / 256;            // coarse buckets (<= 256)
    const int chunk = (E + NBLK - 1) / NBLK;

    uint8_t* ws = (uint8_t*)d_ws;
    size_t off = 0;
    auto alloc = [&](size_t bytes) -> void* {
        void* p = ws + off;
        off += WS_ALIGN(bytes);
        return p;
    };
    int*  bucket_count = (int*) alloc((size_t)NB * 4);
    int*  bucket_start = (int*) alloc(((size_t)NB + 1) * 4);
    int*  bases        = (int*) alloc((size_t)NBLK * NB * 4);
    int*  rowptr       = (int*) alloc(((size_t)N + 1) * 4);
    int2* bk           = (int2*)alloc((size_t)E * 8);
    int2* edges        = (int2*)alloc((size_t)E * 8);
    unsigned short* w1p     = (unsigned short*)alloc((size_t)128 * 128 * 2);
    unsigned short* w2p     = (unsigned short*)alloc((size_t)128 * 64 * 2);
    unsigned short* xw1b    = (unsigned short*)alloc((size_t)N * 128 * 2);
    unsigned short* hb      = (unsigned short*)alloc((size_t)N * 128 * 2);
    unsigned short* logitsb = (unsigned short*)alloc((size_t)N * 64 * 2);
    unsigned short* softb   = (unsigned short*)alloc((size_t)N * 64 * 2);
    unsigned short* labA    = (unsigned short*)alloc((size_t)N * 64 * 2);
    unsigned short* labB    = (unsigned short*)alloc((size_t)N * 64 * 2);

    float* out0 = (float*)d_out;             // x_out [N,64]
    float* out1 = out0 + (size_t)N * 64;     // labels [N,64]

    hipMemsetAsync(bucket_count, 0, (size_t)NB * 4, stream);

    // CSR build: counting sort, LDS atomics only (+50k block-level globals)
    binA_count<<<NBLK, 256, 0, stream>>>(row, bucket_count, bases, E, chunk, NB);
    bin_scan<<<1, 256, 0, stream>>>(bucket_count, bucket_start, NB);
    binA_scatter<<<NBLK, 256, 0, stream>>>(row, colv, ea, bucket_start, bases, bk, E, chunk, NB);
    binB<<<NB, 256, 0, stream>>>(bk, bucket_start, rowptr, edges, N);

    // soft -> bf16; w1, w2 -> packed bf16 fragments (x cvt fused into gemm128)
    const int ns2 = (N * 64) / 2;
    f32_to_bf16_kernel<<<(ns2 + 255) / 256, 256, 0, stream>>>(soft, softb, ns2);
    pack_w_kernel<128><<<8, 256, 0, stream>>>(w1, w1p);
    pack_w_kernel<64><<<4, 256, 0, stream>>>(w2, w2p);

    const int gGemm = (N + 63) / 64;
    const int gSp   = (N + 3) / 4;

    gemm_mfma_f32a<128><<<gGemm, 256, 0, stream>>>(x, w1p, xw1b, N);     // xw1 (bf16)

    // fused pass 1: h = relu(spmm(xw1)+b1), lab1 = spmm(soft)
    fused1_pair<<<gSp, 256, 0, stream>>>(rowptr, edges, (const uint2*)xw1b,
                                         (const unsigned*)softb, b1,
                                         (uint2*)hb, (unsigned*)labA, N);

    gemm_mfma<64><<<gGemm, 256, 0, stream>>>(hb, w2p, logitsb, N);       // logits (bf16)

    // fused pass 2: out0 = sigmoid(spmm(logits)+b2), lab2 = spmm(lab1)
    fused2_pair<<<gSp, 256, 0, stream>>>(rowptr, edges, (const unsigned*)logitsb,
                                         (const unsigned*)labA, b2,
                                         out0, (unsigned*)labB, N);

    // LPA tail (dependent): lab3, lab4, out1
    spmm64_pair<0><<<gSp, 256, 0, stream>>>(rowptr, edges, (const unsigned*)labB, labA, N);
    spmm64_pair<0><<<gSp, 256, 0, stream>>>(rowptr, edges, (const unsigned*)labA, labB, N);
    spmm64_pair<3><<<gSp, 256, 0, stream>>>(rowptr, edges, (const unsigned*)labB, out1, N);
}